// Round 1
// baseline (5926.683 us; speedup 1.0000x reference)
//
#include <hip/hip_runtime.h>
#include <hip/hip_bf16.h>

// LSTM decoder, B=1024, H=300, 256 steps. Output fp32.
// Folded recurrence: W_fold = W_hh + W_ih@W_out (gates from h_t), y = h_t@W_out^T.
// R5: ONE PERSISTENT KERNEL for all 256 steps (247 blocks, 1 block/CU, device-scope
// barrier per step). W fragments resident in LDS (loaded once), c in registers,
// h hi/lo fragments ping-pong through MALL with non-temporal stores.

typedef __attribute__((ext_vector_type(8))) short bf16x8;
typedef __attribute__((ext_vector_type(4))) float f32x4;

#define MFMA16(a, b, c) __builtin_amdgcn_mfma_f32_16x16x32_bf16((a), (b), (c), 0, 0, 0)

__device__ __forceinline__ float sigf(float x) { return 1.0f / (1.0f + __expf(-x)); }
__device__ __forceinline__ float tanh_fast(float x) { return 2.0f / (1.0f + __expf(-2.0f * x)) - 1.0f; }
__device__ __forceinline__ short f2bf(float x) { __hip_bfloat16 h = __float2bfloat16(x); return *(short*)&h; }
__device__ __forceinline__ float bf2f(short s) { __hip_bfloat16 h; *(short*)&h = s; return __bfloat162float(h); }

// ---------- precompute: zero h-frag buffers (65 m-tiles x 4 arrays), copy W_out rows + b_out, zero barrier ----------
__global__ void build_kernel(const float* __restrict__ W_out, const float* __restrict__ b_out,
                             float* __restrict__ W_big, float* __restrict__ bias_big,
                             unsigned int* __restrict__ hfrag_zero, unsigned int* __restrict__ bar) {
    int stride = gridDim.x * blockDim.x;
    int idx = blockIdx.x * blockDim.x + threadIdx.x;
    for (int i = idx; i < 665600; i += stride) hfrag_zero[i] = 0u;  // 4 x 332800 shorts
    for (int i = idx; i < 300 * 300; i += stride) W_big[1200 * 300 + i] = W_out[i];
    for (int i = idx; i < 300; i += stride) bias_big[1200 + i] = b_out[i];
    if (idx < 64) bar[idx] = 0u;
}

// ---------- precompute: W_big rows 0..1199 = W_hh + W_ih @ W_out ----------
__global__ __launch_bounds__(128) void fold_kernel(const float* __restrict__ W_ih,
                                                   const float* __restrict__ W_hh,
                                                   const float* __restrict__ W_out,
                                                   float* __restrict__ W_big) {
    int j = blockIdx.x;  // 0..1199
    __shared__ float row[300];
    for (int m = threadIdx.x; m < 300; m += 128) row[m] = W_ih[j * 300 + m];
    __syncthreads();
    int k0 = threadIdx.x, k1 = threadIdx.x + 128, k2 = threadIdx.x + 256;
    float a0 = 0.f, a1 = 0.f, a2 = 0.f;
    for (int m = 0; m < 300; ++m) {
        float w = row[m];
        a0 += w * W_out[m * 300 + k0];
        a1 += w * W_out[m * 300 + k1];
        if (k2 < 300) a2 += w * W_out[m * 300 + k2];
    }
    W_big[j * 300 + k0] = W_hh[j * 300 + k0] + a0;
    W_big[j * 300 + k1] = W_hh[j * 300 + k1] + a1;
    if (k2 < 300) W_big[j * 300 + k2] = W_hh[j * 300 + k2] + a2;
}

// ---------- precompute: bias_big[0..1199] = b_ih + b_hh + W_ih @ b_out ----------
__global__ __launch_bounds__(64) void bias_fold_kernel(const float* __restrict__ W_ih,
                                                       const float* __restrict__ b_ih,
                                                       const float* __restrict__ b_hh,
                                                       const float* __restrict__ b_out,
                                                       float* __restrict__ bias_big) {
    int j = blockIdx.x;  // 0..1199
    int lane = threadIdx.x;
    float s = 0.f;
    for (int m = lane; m < 300; m += 64) s += W_ih[j * 300 + m] * b_out[m];
    for (int off = 32; off > 0; off >>= 1) s += __shfl_down(s, off);
    if (lane == 0) bias_big[j] = b_ih[j] + b_hh[j] + s;
}

// ---------- precompute: pack W_big into MFMA B-fragment layout, bf16 hi/lo ----------
// tile index = (jt*5 + ch)*10 + kc ; ch 0..3 = gates (row ch*300+j), 4 = y (row 1200+j).
__global__ __launch_bounds__(64) void pack_w_kernel(const float* __restrict__ W_big,
                                                    short* __restrict__ Wh, short* __restrict__ Wl) {
    int tile = blockIdx.x;  // 0..949
    int jt = tile / 50;
    int rem = tile - jt * 50;
    int ch = rem / 10;
    int kc = rem - ch * 10;
    int lane = threadIdx.x;
    int j = jt * 16 + (lane & 15);
    int kbase = kc * 32 + (lane >> 4) * 8;
    int r = (ch < 4) ? (ch * 300 + j) : (1200 + j);
    size_t base = (size_t)tile * 512 + (size_t)lane * 8;
#pragma unroll
    for (int jj = 0; jj < 8; ++jj) {
        int k = kbase + jj;
        float v = (j < 300 && k < 300) ? W_big[(size_t)r * 300 + k] : 0.f;
        short hi = f2bf(v);
        short lo = f2bf(v - bf2f(hi));
        Wh[base + jj] = hi;
        Wl[base + jj] = lo;
    }
}

// ---------- step 0: exact fp32 VALU LSTM cell on [start | h0], K=600 ----------
__global__ __launch_bounds__(128) void step0_kernel(
    const float* __restrict__ x_in, const float* __restrict__ h_in,
    const float* __restrict__ W_ih, const float* __restrict__ W_hh,
    const float* __restrict__ b_ih, const float* __restrict__ b_hh,
    const float* __restrict__ c_in, float* __restrict__ c_out,
    float* __restrict__ h_out) {
    __shared__ float hs[16][68];
    __shared__ float wsm[16][32];
    const int t = threadIdx.x;
    const int bm0 = blockIdx.x * 64;
    const int jg0 = blockIdx.y * 8;

    const int row_idx = t & 31;
    const int wkq = (t >> 5) << 2;
    const int jl = row_idx >> 2, g = row_idx & 3;
    const int grow = jg0 + jl + 300 * g;
    const bool wvalid = (jg0 + jl) < 300;

    float acc[4][4];
#pragma unroll
    for (int i = 0; i < 4; ++i)
#pragma unroll
        for (int q = 0; q < 4; ++q) acc[i][q] = 0.f;

    for (int it = 0; it < 38; ++it) {
        const int k0 = it << 4;
#pragma unroll
        for (int q = 0; q < 2; ++q) {
            int qi = t + q * 128;
            int bl = qi >> 2;
            int kq = (qi & 3) << 2;
            int kg = k0 + kq;
            float4 hv = make_float4(0.f, 0.f, 0.f, 0.f);
            if (kg < 600) {
                const float* src = (kg < 300) ? (x_in + (size_t)(bm0 + bl) * 300 + kg)
                                              : (h_in + (size_t)(bm0 + bl) * 300 + (kg - 300));
                hv = *(const float4*)src;
            }
            hs[kq + 0][bl] = hv.x;
            hs[kq + 1][bl] = hv.y;
            hs[kq + 2][bl] = hv.z;
            hs[kq + 3][bl] = hv.w;
        }
        {
            int kg = k0 + wkq;
            float4 wv = make_float4(0.f, 0.f, 0.f, 0.f);
            if (wvalid && kg < 600) {
                const float* src = (kg < 300) ? (W_ih + (size_t)grow * 300 + kg)
                                              : (W_hh + (size_t)grow * 300 + (kg - 300));
                wv = *(const float4*)src;
            }
            wsm[wkq + 0][row_idx] = wv.x;
            wsm[wkq + 1][row_idx] = wv.y;
            wsm[wkq + 2][row_idx] = wv.z;
            wsm[wkq + 3][row_idx] = wv.w;
        }
        __syncthreads();
        const int bs4 = (t & 15) << 2;
        const int c4 = (t >> 4) << 2;
#pragma unroll
        for (int k = 0; k < 16; ++k) {
            float4 hv = *(const float4*)&hs[k][bs4];
            float4 wv = *(const float4*)&wsm[k][c4];
            float hvv[4] = {hv.x, hv.y, hv.z, hv.w};
            float wvv[4] = {wv.x, wv.y, wv.z, wv.w};
#pragma unroll
            for (int bi = 0; bi < 4; ++bi)
#pragma unroll
                for (int q = 0; q < 4; ++q) acc[bi][q] += hvv[bi] * wvv[q];
        }
        __syncthreads();
    }

    const int b0 = bm0 + ((t & 15) << 2);
    const int j = jg0 + (t >> 4);
    if (j < 300) {
        const float bi_ = b_ih[j] + b_hh[j];
        const float bf_ = b_ih[j + 300] + b_hh[j + 300];
        const float bg_ = b_ih[j + 600] + b_hh[j + 600];
        const float bo_ = b_ih[j + 900] + b_hh[j + 900];
#pragma unroll
        for (int bi = 0; bi < 4; ++bi) {
            const int b = b0 + bi;
            float ig = sigf(acc[bi][0] + bi_);
            float fg = sigf(acc[bi][1] + bf_);
            float gg = tanh_fast(acc[bi][2] + bg_);
            float og = sigf(acc[bi][3] + bo_);
            float cn = fg * c_in[(size_t)b * 300 + j] + ig * gg;
            c_out[(size_t)b * 300 + j] = cn;
            h_out[(size_t)b * 300 + j] = og * tanh_fast(cn);
        }
    }
}

// ---------- convert h fp32 -> A-fragment layout bf16 hi/lo ----------
__global__ __launch_bounds__(256) void convert_h_kernel(const float* __restrict__ h_row,
                                                        short* __restrict__ Hh, short* __restrict__ Hl) {
    int idx = blockIdx.x * 256 + threadIdx.x;  // 1024*320
    int m = idx / 320;
    int k = idx - m * 320;
    float v = (k < 300) ? h_row[(size_t)m * 300 + k] : 0.f;
    short hi = f2bf(v);
    short lo = f2bf(v - bf2f(hi));
    int chunk = k >> 5;
    int lane = (m & 15) + 16 * ((k & 31) >> 3);
    int slot = k & 7;
    size_t fi = (((size_t)(m >> 4) * 10 + chunk) * 64 + lane) * 8 + slot;
    Hh[fi] = hi;
    Hl[fi] = lo;
}

// ---------- R5 persistent kernel: all 256 steps, 247 blocks x 256 threads ----------
// Block (jt, mg): 16 output cols (jt of 19) x 80 rows (mg of 13; m padded to 1040,
// A-tile 64 is zero). Waves: w0: ch{i,f} x mt{0,1,2}; w1: ch{i,f} x mt{3,4} + y x mt{3,4};
// w2: ch{g,o} x mt{0,1,2}; w3: ch{g,o} x mt{3,4} + y x mt{0,1,2}.  (18/16/18/18 MFMA per kc)
// W frags resident in LDS; A streamed per 2-kc chunk (reg-staged, double-buffered);
// c in registers; B/y written non-temporal; device-scope barrier per step.
__global__ __launch_bounds__(256, 1) void persist_kernel(
    short* __restrict__ H0h, short* __restrict__ H0l,
    short* __restrict__ H1h, short* __restrict__ H1l,
    const short* __restrict__ Wph, const short* __restrict__ Wpl,
    const float* __restrict__ bias, const float* __restrict__ c_init,
    float* __restrict__ out, unsigned int* __restrict__ bar) {
    __shared__ __align__(16) short w_hi[5 * 10 * 512];      // 51200 B
    __shared__ __align__(16) short w_lo[4 * 10 * 512];      // 40960 B
    __shared__ __align__(16) short a_sm[2 * 2 * 2 * 5 * 512];  // 40960 B (dbuf x kcL x prec x mt)
    __shared__ float gbuf[5][80][17];                       // 27200 B (ch i,f,g,o,y)
    __shared__ float bias_s[80];                            // 320 B       => 160640 B total

    const int bid = blockIdx.x;
    // XCD-grouped mapping: blocks with bid%8==x get contiguous seq -> same-mg blocks share an XCD L2
    const int seq = (bid & 7) * 31 + (bid >> 3);  // bijective onto [0,247)
    const int mg = seq / 19;                      // 0..12 (rows mg*80..+80)
    const int jt = seq - mg * 19;                 // 0..18 (cols jt*16..+16)
    const int tid = threadIdx.x;
    const int wave = tid >> 6;
    const int lane = tid & 63;

    // one-time: W tiles for this jt -> LDS (hi: ch 0..4, lo: ch 0..3)
    {
        const int4* s1 = (const int4*)(Wph + (size_t)jt * 25600);
        int4* d1 = (int4*)w_hi;
        for (int i = tid; i < 3200; i += 256) d1[i] = s1[i];
        const int4* s2 = (const int4*)(Wpl + (size_t)jt * 25600);
        int4* d2 = (int4*)w_lo;
        for (int i = tid; i < 2560; i += 256) d2[i] = s2[i];
        if (tid < 80) {
            const int cch = tid >> 4, jl = tid & 15;
            const int j = jt * 16 + jl;
            bias_s[tid] = (j < 300) ? bias[cch * 300 + j] : 0.f;
        }
    }

    // c state in registers (owner-computes, never written back)
    float c_reg[5];
#pragma unroll
    for (int k = 0; k < 5; ++k) {
        const int e = tid + (k << 8);
        const int ml = e >> 4, jl = e & 15;
        const int j = jt * 16 + jl;
        const int m = mg * 80 + ml;
        c_reg[k] = (j < 300 && m < 1024) ? c_init[(size_t)m * 300 + j] : 0.f;
    }

    // wave roles
    const int chb = (wave >> 1) << 1;                       // 0 or 2
    const int gmlo = (wave & 1) ? 3 : 0;
    const int gcnt = (wave & 1) ? 2 : 3;
    const int ycnt = (wave == 1) ? 2 : ((wave == 3) ? 3 : 0);
    const int ymlo = (wave == 1) ? 3 : 0;

    const short* whB = w_hi + chb * 5120 + (lane << 3);
    const short* wlB = w_lo + chb * 5120 + (lane << 3);
    const short* wyB = w_hi + 4 * 5120 + (lane << 3);
    const short* aB = a_sm + (lane << 3);

    const int jlc = lane & 15;
    const int mr = ((lane >> 4) << 2);

#pragma unroll 1
    for (int tt = 1; tt <= 256; ++tt) {
        const short* Ah = (tt & 1) ? H0h : H1h;
        const short* Al = (tt & 1) ? H0l : H1l;
        short* Bh = (tt & 1) ? H1h : H0h;
        short* Bl = (tt & 1) ? H1l : H0l;
        float* yo = out + (size_t)(tt - 1) * 307200;

        f32x4 acc[2][3];
        f32x4 accy[3];
#pragma unroll
        for (int c = 0; c < 2; ++c)
#pragma unroll
            for (int i = 0; i < 3; ++i) acc[c][i] = (f32x4){0.f, 0.f, 0.f, 0.f};
#pragma unroll
        for (int i = 0; i < 3; ++i) accy[i] = (f32x4){0.f, 0.f, 0.f, 0.f};

        // prologue: stage chunk 0 -> buffer 0 (20 ops of 1KB, 5 per wave)
        {
            int4 st[5];
#pragma unroll
            for (int i = 0; i < 5; ++i) {
                const int o = wave + (i << 2);
                const int mt = o % 5, prec = (o / 5) & 1, kcL = o / 10;
                const short* src = prec ? Al : Ah;
                st[i] = ((const int4*)(src + ((size_t)((mg * 5 + mt) * 10 + kcL) << 9)))[lane];
            }
#pragma unroll
            for (int i = 0; i < 5; ++i) {
                const int o = wave + (i << 2);
                const int mt = o % 5, prec = (o / 5) & 1, kcL = o / 10;
                ((int4*)(a_sm + ((size_t)((((kcL << 1) | prec) * 5 + mt)) << 9)))[lane] = st[i];
            }
        }
        __syncthreads();

#pragma unroll
        for (int nc = 0; nc < 5; ++nc) {
            const int rb = nc & 1;
            int4 st[5];
            if (nc < 4) {  // issue next-chunk global loads first (latency hides under MFMA)
#pragma unroll
                for (int i = 0; i < 5; ++i) {
                    const int o = wave + (i << 2);
                    const int mt = o % 5, prec = (o / 5) & 1, kcL = o / 10;
                    const short* src = prec ? Al : Ah;
                    st[i] = ((const int4*)(src +
                              ((size_t)((mg * 5 + mt) * 10 + (nc * 2 + 2 + kcL)) << 9)))[lane];
                }
            }
#pragma unroll
            for (int kcL = 0; kcL < 2; ++kcL) {
                const int kc = nc * 2 + kcL;
                const bf16x8 bh0 = *(const bf16x8*)(whB + (kc << 9));
                const bf16x8 bh1 = *(const bf16x8*)(whB + ((10 + kc) << 9));
                const bf16x8 bl0 = *(const bf16x8*)(wlB + (kc << 9));
                const bf16x8 bl1 = *(const bf16x8*)(wlB + ((10 + kc) << 9));
                const short* ab = aB + (((rb << 1) | kcL) * 5120);
#pragma unroll
                for (int mti = 0; mti < 3; ++mti) {
                    if (mti < gcnt) {
                        const int mt = gmlo + mti;
                        const bf16x8 ah = *(const bf16x8*)(ab + (mt << 9));
                        const bf16x8 al = *(const bf16x8*)(ab + ((5 + mt) << 9));
                        acc[0][mti] = MFMA16(ah, bh0, acc[0][mti]);
                        acc[0][mti] = MFMA16(al, bh0, acc[0][mti]);
                        acc[0][mti] = MFMA16(ah, bl0, acc[0][mti]);
                        acc[1][mti] = MFMA16(ah, bh1, acc[1][mti]);
                        acc[1][mti] = MFMA16(al, bh1, acc[1][mti]);
                        acc[1][mti] = MFMA16(ah, bl1, acc[1][mti]);
                    }
                }
                if (ycnt) {
                    const bf16x8 byh = *(const bf16x8*)(wyB + (kc << 9));
#pragma unroll
                    for (int yi = 0; yi < 3; ++yi) {
                        if (yi < ycnt) {
                            const int mt = ymlo + yi;
                            const bf16x8 ah = *(const bf16x8*)(ab + (mt << 9));
                            const bf16x8 al = *(const bf16x8*)(ab + ((5 + mt) << 9));
                            accy[yi] = MFMA16(ah, byh, accy[yi]);
                            accy[yi] = MFMA16(al, byh, accy[yi]);
                        }
                    }
                }
            }
            if (nc < 4) {
                const int wb = rb ^ 1;
#pragma unroll
                for (int i = 0; i < 5; ++i) {
                    const int o = wave + (i << 2);
                    const int mt = o % 5, prec = (o / 5) & 1, kcL = o / 10;
                    ((int4*)(a_sm + ((size_t)(((((wb << 1) | kcL) << 1) | prec) * 5 + mt) << 9)))[lane] = st[i];
                }
            }
            __syncthreads();
        }

        // gates/y -> LDS. C/D: col=lane&15 (j local), row=(lane>>4)*4+r (m within tile)
#pragma unroll
        for (int c = 0; c < 2; ++c)
#pragma unroll
            for (int mti = 0; mti < 3; ++mti) {
                if (mti < gcnt) {
#pragma unroll
                    for (int r = 0; r < 4; ++r)
                        gbuf[chb + c][(gmlo + mti) * 16 + mr + r][jlc] = acc[c][mti][r];
                }
            }
        if (ycnt) {
#pragma unroll
            for (int yi = 0; yi < 3; ++yi) {
                if (yi < ycnt) {
#pragma unroll
                    for (int r = 0; r < 4; ++r)
                        gbuf[4][(ymlo + yi) * 16 + mr + r][jlc] = accy[yi][r];
                }
            }
        }
        __syncthreads();

        // pointwise epilogue: c update (regs), next-h frags (nt), y (nt)
#pragma unroll
        for (int k = 0; k < 5; ++k) {
            const int e = tid + (k << 8);
            const int ml = e >> 4, jl = e & 15;
            const int j = jt * 16 + jl;
            const int m = mg * 80 + ml;
            if (j < 300 && m < 1024) {
                const float gi = gbuf[0][ml][jl] + bias_s[jl];
                const float gf = gbuf[1][ml][jl] + bias_s[16 + jl];
                const float gg = gbuf[2][ml][jl] + bias_s[32 + jl];
                const float go_ = gbuf[3][ml][jl] + bias_s[48 + jl];
                const float iv = sigf(gi), fv = sigf(gf), gv = tanh_fast(gg), ov = sigf(go_);
                const float cn = fv * c_reg[k] + iv * gv;
                c_reg[k] = cn;
                const float hv = ov * tanh_fast(cn);
                const float yv = gbuf[4][ml][jl] + bias_s[64 + jl];
                __builtin_nontemporal_store(yv, yo + (size_t)m * 300 + j);
                const short hb = f2bf(hv);
                const short lb = f2bf(hv - bf2f(hb));
                const int chk = j >> 5;
                const int lane_a = (m & 15) + (((j & 31) >> 3) << 4);
                const int slot = j & 7;
                const size_t fi = ((((size_t)(m >> 4) * 10 + chk) << 6) + lane_a) * 8 + slot;
                __builtin_nontemporal_store(hb, Bh + fi);
                __builtin_nontemporal_store(lb, Bl + fi);
            }
        }

        // device-scope grid barrier (sense-free, monotonic counter + step flag)
        __syncthreads();
        if (tid == 0) {
            __threadfence();  // release: prior writes visible at agent scope
            const unsigned prev =
                __hip_atomic_fetch_add(&bar[0], 1u, __ATOMIC_RELAXED, __HIP_MEMORY_SCOPE_AGENT);
            if (prev == (unsigned)(247 * tt - 1)) {
                __hip_atomic_store(&bar[32], (unsigned)tt, __ATOMIC_RELAXED, __HIP_MEMORY_SCOPE_AGENT);
            } else {
                while (__hip_atomic_load(&bar[32], __ATOMIC_RELAXED, __HIP_MEMORY_SCOPE_AGENT) <
                       (unsigned)tt) {
                    __builtin_amdgcn_s_sleep(2);
                }
            }
            __threadfence();  // acquire: invalidate L1/L2 before next step's A reads
        }
        __syncthreads();
    }
}

extern "C" void kernel_launch(void* const* d_in, const int* in_sizes, int n_in,
                              void* d_out, int out_size, void* d_ws, size_t ws_size,
                              hipStream_t stream) {
    const float* h0 = (const float*)d_in[0];
    const float* c0 = (const float*)d_in[1];
    const float* start = (const float*)d_in[2];
    const float* W_ih = (const float*)d_in[3];
    const float* W_hh = (const float*)d_in[4];
    const float* b_ih = (const float*)d_in[5];
    const float* b_hh = (const float*)d_in[6];
    const float* W_out = (const float*)d_in[7];
    const float* b_out = (const float*)d_in[8];
    float* out = (float*)d_out;

    float* wsf = (float*)d_ws;
    float* W_big = wsf;               // 450000
    float* bias_big = wsf + 450000;   // 1504
    float* c_ws = wsf + 451504;       // 307200
    float* h_row = wsf + 758704;      // 307200
    short* wss = (short*)(wsf + 1065904);
    short* Wh = wss;                  // 486400
    short* Wl = wss + 486400;         // 486400
    short* H0h = wss + 972800;        // 332800 (65 m-tiles: tile 64 stays zero)
    short* H0l = wss + 1305600;       // 332800
    short* H1h = wss + 1638400;       // 332800
    short* H1l = wss + 1971200;       // 332800
    unsigned int* bar = (unsigned int*)(wss + 2304000);  // 64 uints

    build_kernel<<<2816, 256, 0, stream>>>(W_out, b_out, W_big, bias_big, (unsigned int*)H0h, bar);
    fold_kernel<<<1200, 128, 0, stream>>>(W_ih, W_hh, W_out, W_big);
    bias_fold_kernel<<<1200, 64, 0, stream>>>(W_ih, b_ih, b_hh, b_out, bias_big);
    pack_w_kernel<<<950, 64, 0, stream>>>(W_big, Wh, Wl);

    // step 0 (ref iteration 0): exact fp32; h_1 -> h_row, c_1 -> c_ws
    step0_kernel<<<dim3(16, 38), 128, 0, stream>>>(start, h0, W_ih, W_hh, b_ih, b_hh,
                                                   c0, c_ws, h_row);
    convert_h_kernel<<<1280, 256, 0, stream>>>(h_row, H0h, H0l);

    // tt = 1..256 all inside one persistent kernel (247 blocks, 1/CU by 160KB LDS)
    persist_kernel<<<247, 256, 0, stream>>>(H0h, H0l, H1h, H1l, Wh, Wl,
                                            bias_big, c_ws, out, bar);
}

// Round 3
// 5133.405 us; speedup vs baseline: 1.1545x; 1.1545x over previous
//
#include <hip/hip_runtime.h>
#include <hip/hip_bf16.h>

// LSTM decoder, B=1024, H=300, 256 steps. Output fp32.
// Folded recurrence: W_fold = W_hh + W_ih@W_out (gates from h_t), y = h_t@W_out^T.
// R7: barrier-free persistent kernel (fixed). Topology from R6: 152 blocks =
// 8 row-groups x 19 j-tiles, 1 block/CU, W resident in LDS, c in registers,
// in-register epilogue, per-group point-to-point sync (no grid barrier).
// Coherence = R5-proven protocol: plain compiler-visible loads/stores (compiler
// manages waitcnts -> no async-VGPR hazard), __threadfence() release/acquire
// (wbL2 + invL2), relaxed agent-scope atomic flags. One fence+flag per block/step.

typedef __attribute__((ext_vector_type(8))) short bf16x8;
typedef __attribute__((ext_vector_type(4))) float f32x4;

#define MFMA16(a, b, c) __builtin_amdgcn_mfma_f32_16x16x32_bf16((a), (b), (c), 0, 0, 0)

__device__ __forceinline__ float sigf(float x) { return 1.0f / (1.0f + __expf(-x)); }
__device__ __forceinline__ float tanh_fast(float x) { return 2.0f / (1.0f + __expf(-2.0f * x)) - 1.0f; }
__device__ __forceinline__ short f2bf(float x) { __hip_bfloat16 h = __float2bfloat16(x); return *(short*)&h; }
__device__ __forceinline__ float bf2f(short s) { __hip_bfloat16 h; *(short*)&h = s; return __bfloat162float(h); }

// ---------- precompute: zero h-frag buffers + flags, copy W_out rows + b_out ----------
__global__ void build_kernel(const float* __restrict__ W_out, const float* __restrict__ b_out,
                             float* __restrict__ W_big, float* __restrict__ bias_big,
                             unsigned int* __restrict__ hfrag_zero, unsigned int* __restrict__ flags) {
    int stride = gridDim.x * blockDim.x;
    int idx = blockIdx.x * blockDim.x + threadIdx.x;
    for (int i = idx; i < 655360; i += stride) hfrag_zero[i] = 0u;  // 4 x 327680 shorts
    for (int i = idx; i < 300 * 300; i += stride) W_big[1200 * 300 + i] = W_out[i];
    for (int i = idx; i < 300; i += stride) bias_big[1200 + i] = b_out[i];
    if (idx < 256) flags[idx] = 0u;
}

// ---------- precompute: W_big rows 0..1199 = W_hh + W_ih @ W_out ----------
__global__ __launch_bounds__(128) void fold_kernel(const float* __restrict__ W_ih,
                                                   const float* __restrict__ W_hh,
                                                   const float* __restrict__ W_out,
                                                   float* __restrict__ W_big) {
    int j = blockIdx.x;  // 0..1199
    __shared__ float row[300];
    for (int m = threadIdx.x; m < 300; m += 128) row[m] = W_ih[j * 300 + m];
    __syncthreads();
    int k0 = threadIdx.x, k1 = threadIdx.x + 128, k2 = threadIdx.x + 256;
    float a0 = 0.f, a1 = 0.f, a2 = 0.f;
    for (int m = 0; m < 300; ++m) {
        float w = row[m];
        a0 += w * W_out[m * 300 + k0];
        a1 += w * W_out[m * 300 + k1];
        if (k2 < 300) a2 += w * W_out[m * 300 + k2];
    }
    W_big[j * 300 + k0] = W_hh[j * 300 + k0] + a0;
    W_big[j * 300 + k1] = W_hh[j * 300 + k1] + a1;
    if (k2 < 300) W_big[j * 300 + k2] = W_hh[j * 300 + k2] + a2;
}

// ---------- precompute: bias_big[0..1199] = b_ih + b_hh + W_ih @ b_out ----------
__global__ __launch_bounds__(64) void bias_fold_kernel(const float* __restrict__ W_ih,
                                                       const float* __restrict__ b_ih,
                                                       const float* __restrict__ b_hh,
                                                       const float* __restrict__ b_out,
                                                       float* __restrict__ bias_big) {
    int j = blockIdx.x;  // 0..1199
    int lane = threadIdx.x;
    float s = 0.f;
    for (int m = lane; m < 300; m += 64) s += W_ih[j * 300 + m] * b_out[m];
    for (int off = 32; off > 0; off >>= 1) s += __shfl_down(s, off);
    if (lane == 0) bias_big[j] = b_ih[j] + b_hh[j] + s;
}

// ---------- precompute: pack W_big into MFMA B-fragment layout, bf16 hi/lo ----------
// tile index = (jt*5 + ch)*10 + kc ; ch 0..3 = gates (row ch*300+j), 4 = y (row 1200+j).
__global__ __launch_bounds__(64) void pack_w_kernel(const float* __restrict__ W_big,
                                                    short* __restrict__ Wh, short* __restrict__ Wl) {
    int tile = blockIdx.x;  // 0..949
    int jt = tile / 50;
    int rem = tile - jt * 50;
    int ch = rem / 10;
    int kc = rem - ch * 10;
    int lane = threadIdx.x;
    int j = jt * 16 + (lane & 15);
    int kbase = kc * 32 + (lane >> 4) * 8;
    int r = (ch < 4) ? (ch * 300 + j) : (1200 + j);
    size_t base = (size_t)tile * 512 + (size_t)lane * 8;
#pragma unroll
    for (int jj = 0; jj < 8; ++jj) {
        int k = kbase + jj;
        float v = (j < 300 && k < 300) ? W_big[(size_t)r * 300 + k] : 0.f;
        short hi = f2bf(v);
        short lo = f2bf(v - bf2f(hi));
        Wh[base + jj] = hi;
        Wl[base + jj] = lo;
    }
}

// ---------- step 0: exact fp32 VALU LSTM cell on [start | h0], K=600 ----------
__global__ __launch_bounds__(128) void step0_kernel(
    const float* __restrict__ x_in, const float* __restrict__ h_in,
    const float* __restrict__ W_ih, const float* __restrict__ W_hh,
    const float* __restrict__ b_ih, const float* __restrict__ b_hh,
    const float* __restrict__ c_in, float* __restrict__ c_out,
    float* __restrict__ h_out) {
    __shared__ float hs[16][68];
    __shared__ float wsm[16][32];
    const int t = threadIdx.x;
    const int bm0 = blockIdx.x * 64;
    const int jg0 = blockIdx.y * 8;

    const int row_idx = t & 31;
    const int wkq = (t >> 5) << 2;
    const int jl = row_idx >> 2, g = row_idx & 3;
    const int grow = jg0 + jl + 300 * g;
    const bool wvalid = (jg0 + jl) < 300;

    float acc[4][4];
#pragma unroll
    for (int i = 0; i < 4; ++i)
#pragma unroll
        for (int q = 0; q < 4; ++q) acc[i][q] = 0.f;

    for (int it = 0; it < 38; ++it) {
        const int k0 = it << 4;
#pragma unroll
        for (int q = 0; q < 2; ++q) {
            int qi = t + q * 128;
            int bl = qi >> 2;
            int kq = (qi & 3) << 2;
            int kg = k0 + kq;
            float4 hv = make_float4(0.f, 0.f, 0.f, 0.f);
            if (kg < 600) {
                const float* src = (kg < 300) ? (x_in + (size_t)(bm0 + bl) * 300 + kg)
                                              : (h_in + (size_t)(bm0 + bl) * 300 + (kg - 300));
                hv = *(const float4*)src;
            }
            hs[kq + 0][bl] = hv.x;
            hs[kq + 1][bl] = hv.y;
            hs[kq + 2][bl] = hv.z;
            hs[kq + 3][bl] = hv.w;
        }
        {
            int kg = k0 + wkq;
            float4 wv = make_float4(0.f, 0.f, 0.f, 0.f);
            if (wvalid && kg < 600) {
                const float* src = (kg < 300) ? (W_ih + (size_t)grow * 300 + kg)
                                              : (W_hh + (size_t)grow * 300 + (kg - 300));
                wv = *(const float4*)src;
            }
            wsm[wkq + 0][row_idx] = wv.x;
            wsm[wkq + 1][row_idx] = wv.y;
            wsm[wkq + 2][row_idx] = wv.z;
            wsm[wkq + 3][row_idx] = wv.w;
        }
        __syncthreads();
        const int bs4 = (t & 15) << 2;
        const int c4 = (t >> 4) << 2;
#pragma unroll
        for (int k = 0; k < 16; ++k) {
            float4 hv = *(const float4*)&hs[k][bs4];
            float4 wv = *(const float4*)&wsm[k][c4];
            float hvv[4] = {hv.x, hv.y, hv.z, hv.w};
            float wvv[4] = {wv.x, wv.y, wv.z, wv.w};
#pragma unroll
            for (int bi = 0; bi < 4; ++bi)
#pragma unroll
                for (int q = 0; q < 4; ++q) acc[bi][q] += hvv[bi] * wvv[q];
        }
        __syncthreads();
    }

    const int b0 = bm0 + ((t & 15) << 2);
    const int j = jg0 + (t >> 4);
    if (j < 300) {
        const float bi_ = b_ih[j] + b_hh[j];
        const float bf_ = b_ih[j + 300] + b_hh[j + 300];
        const float bg_ = b_ih[j + 600] + b_hh[j + 600];
        const float bo_ = b_ih[j + 900] + b_hh[j + 900];
#pragma unroll
        for (int bi = 0; bi < 4; ++bi) {
            const int b = b0 + bi;
            float ig = sigf(acc[bi][0] + bi_);
            float fg = sigf(acc[bi][1] + bf_);
            float gg = tanh_fast(acc[bi][2] + bg_);
            float og = sigf(acc[bi][3] + bo_);
            float cn = fg * c_in[(size_t)b * 300 + j] + ig * gg;
            c_out[(size_t)b * 300 + j] = cn;
            h_out[(size_t)b * 300 + j] = og * tanh_fast(cn);
        }
    }
}

// ---------- convert h fp32 -> A-fragment layout bf16 hi/lo ----------
__global__ __launch_bounds__(256) void convert_h_kernel(const float* __restrict__ h_row,
                                                        short* __restrict__ Hh, short* __restrict__ Hl) {
    int idx = blockIdx.x * 256 + threadIdx.x;  // 1024*320
    int m = idx / 320;
    int k = idx - m * 320;
    float v = (k < 300) ? h_row[(size_t)m * 300 + k] : 0.f;
    short hi = f2bf(v);
    short lo = f2bf(v - bf2f(hi));
    int chunk = k >> 5;
    int lane = (m & 15) + 16 * ((k & 31) >> 3);
    int slot = k & 7;
    size_t fi = (((size_t)(m >> 4) * 10 + chunk) * 64 + lane) * 8 + slot;
    Hh[fi] = hi;
    Hl[fi] = lo;
}

// ---------- R7 persistent kernel: 152 blocks = 8 groups x 19 jt, 256 thr (4 waves) ----------
// Wave w owns m-tiles {g*8+w, g*8+w+4} end-to-end (independent planes; no intra-step
// wave exchange). Per-step sync: block computes, __syncthreads, tid0 threadfence
// (release: wbL2) + relaxed agent atomic flag; consumers: wave0 polls 19 flags,
// threadfence (acquire: invL2), __syncthreads, then plain A-fragment loads.
__global__ __launch_bounds__(256, 1) void persist_kernel(
    short* __restrict__ H0h, short* __restrict__ H0l,
    short* __restrict__ H1h, short* __restrict__ H1l,
    const short* __restrict__ Wph, const short* __restrict__ Wpl,
    const float* __restrict__ bias, const float* __restrict__ c_init,
    float* __restrict__ out, unsigned* __restrict__ flags) {
    __shared__ __align__(16) short w_hi[50 * 512];  // gates hi (40 tiles) + y hi (10) = 51200 B
    __shared__ __align__(16) short w_lo[40 * 512];  // gates lo = 40960 B  (92160 B -> 1 blk/CU)

    const int bid = blockIdx.x;
    const int g = bid / 19;         // row group: rows g*128 .. +128
    const int jt = bid - g * 19;    // j tile: cols jt*16 .. +16
    const int tid = threadIdx.x;
    const int wave = tid >> 6;
    const int lane = tid & 63;

    // one-time: W tiles for this jt -> LDS
    {
        const int4* s1 = (const int4*)(Wph + (size_t)jt * 25600);
        int4* d1 = (int4*)w_hi;
        for (int i = tid; i < 3200; i += 256) d1[i] = s1[i];
        const int4* s2 = (const int4*)(Wpl + (size_t)jt * 25600);
        int4* d2 = (int4*)w_lo;
        for (int i = tid; i < 2560; i += 256) d2[i] = s2[i];
    }

    const int jl = lane & 15;
    const int jg = jt * 16 + jl;
    const bool jvalid = jg < 300;
    const int mr = (lane >> 4) << 2;
    const int laneo = lane << 3;

    float b_i = 0.f, b_f = 0.f, b_g = 0.f, b_o = 0.f, b_y = 0.f;
    if (jvalid) {
        b_i = bias[jg];
        b_f = bias[300 + jg];
        b_g = bias[600 + jg];
        b_o = bias[900 + jg];
        b_y = bias[1200 + jg];
    }

    const int mt0 = g * 8 + wave;   // this wave's m-tiles: mt0, mt0+4
    float c_reg[8];
#pragma unroll
    for (int mti = 0; mti < 2; ++mti)
#pragma unroll
        for (int r = 0; r < 4; ++r) {
            const int m = (mt0 + 4 * mti) * 16 + mr + r;
            c_reg[mti * 4 + r] = jvalid ? c_init[(size_t)m * 300 + jg] : 0.f;
        }

    // fragment addressing (int4 units): tile mt base = mt*640, kc stride = 64
    const int iA = mt0 * 640 + lane;
    const int chunk = jt >> 1;
    const int halfA = 2 * (jt & 1) + (jl >> 3);
    const int sloti = jl & 7;
    unsigned* fpoll_p = flags + (g * 19 + (lane < 19 ? lane : 18));
    unsigned* fpub_p = flags + (g * 19 + jt);

    __syncthreads();  // W in LDS ready; step-1 inputs visible via launch boundary

#pragma unroll 1
    for (int tt = 1; tt <= 256; ++tt) {
        const short* Ah8 = (tt & 1) ? H0h : H1h;
        const short* Al8 = (tt & 1) ? H0l : H1l;
        short* Bh8 = (tt & 1) ? H1h : H0h;
        short* Bl8 = (tt & 1) ? H1l : H0l;
        float* yo = out + (size_t)(tt - 1) * 307200;

        if (tt > 1) {
            if (wave == 0) {
                const unsigned target = (unsigned)(tt - 1);
                while (true) {
                    unsigned fv = __hip_atomic_load(fpoll_p, __ATOMIC_RELAXED,
                                                    __HIP_MEMORY_SCOPE_AGENT);
                    if (__all((int)((lane >= 19) | (fv >= target)))) break;
                    __builtin_amdgcn_s_sleep(1);
                }
                __threadfence();  // acquire: invalidate L1/L2 before A reads
            }
            __syncthreads();
        }

        const int4* A4h = (const int4*)Ah8 + iA;
        const int4* A4l = (const int4*)Al8 + iA;

        f32x4 acc[4][2];
        f32x4 accy[2];
#pragma unroll
        for (int ch = 0; ch < 4; ++ch) {
            acc[ch][0] = (f32x4){0.f, 0.f, 0.f, 0.f};
            acc[ch][1] = (f32x4){0.f, 0.f, 0.f, 0.f};
        }
        accy[0] = (f32x4){0.f, 0.f, 0.f, 0.f};
        accy[1] = (f32x4){0.f, 0.f, 0.f, 0.f};

        // 2-ahead slot rotation; all indices compile-time after full unroll.
        int4 p0h[3], p0l[3], p1h[3], p1l[3];
        p0h[0] = A4h[0];
        p0l[0] = A4l[0];
        p1h[0] = A4h[2560];
        p1l[0] = A4l[2560];
        p0h[1] = A4h[64];
        p0l[1] = A4l[64];
        p1h[1] = A4h[2624];
        p1l[1] = A4l[2624];

#pragma unroll
        for (int kc = 0; kc < 10; ++kc) {
            const int cs = kc % 3;
            if (kc + 2 < 10) {
                const int ns = (kc + 2) % 3;
                p0h[ns] = A4h[(kc + 2) * 64];
                p0l[ns] = A4l[(kc + 2) * 64];
                p1h[ns] = A4h[2560 + (kc + 2) * 64];
                p1l[ns] = A4l[2560 + (kc + 2) * 64];
            }
            const bf16x8 a0h = *(const bf16x8*)&p0h[cs];
            const bf16x8 a0l = *(const bf16x8*)&p0l[cs];
            const bf16x8 a1h = *(const bf16x8*)&p1h[cs];
            const bf16x8 a1l = *(const bf16x8*)&p1l[cs];
#pragma unroll
            for (int ch = 0; ch < 4; ++ch) {
                const bf16x8 bh = *(const bf16x8*)(w_hi + ((ch * 10 + kc) << 9) + laneo);
                const bf16x8 bl = *(const bf16x8*)(w_lo + ((ch * 10 + kc) << 9) + laneo);
                acc[ch][0] = MFMA16(a0h, bh, acc[ch][0]);
                acc[ch][0] = MFMA16(a0l, bh, acc[ch][0]);
                acc[ch][0] = MFMA16(a0h, bl, acc[ch][0]);
                acc[ch][1] = MFMA16(a1h, bh, acc[ch][1]);
                acc[ch][1] = MFMA16(a1l, bh, acc[ch][1]);
                acc[ch][1] = MFMA16(a1h, bl, acc[ch][1]);
            }
            const bf16x8 by = *(const bf16x8*)(w_hi + ((40 + kc) << 9) + laneo);
            accy[0] = MFMA16(a0h, by, accy[0]);
            accy[0] = MFMA16(a0l, by, accy[0]);
            accy[1] = MFMA16(a1h, by, accy[1]);
            accy[1] = MFMA16(a1l, by, accy[1]);
        }

        // in-register pointwise epilogue (plain stores; compiler-managed waits)
#pragma unroll
        for (int mti = 0; mti < 2; ++mti) {
            const int MT = mt0 + 4 * mti;
#pragma unroll
            for (int r = 0; r < 4; ++r) {
                const float gi = acc[0][mti][r] + b_i;
                const float gf = acc[1][mti][r] + b_f;
                const float gg = acc[2][mti][r] + b_g;
                const float go_ = acc[3][mti][r] + b_o;
                const float iv = sigf(gi), fv = sigf(gf), gv = tanh_fast(gg), ov = sigf(go_);
                const float cn = fv * c_reg[mti * 4 + r] + iv * gv;
                c_reg[mti * 4 + r] = cn;
                const float hv = ov * tanh_fast(cn);
                if (jvalid) {
                    const int m = MT * 16 + mr + r;
                    __builtin_nontemporal_store(accy[mti][r] + b_y, yo + (size_t)m * 300 + jg);
                    const short hb = f2bf(hv);
                    const short lb = f2bf(hv - bf2f(hb));
                    const int lane_a = (mr + r) + (halfA << 4);
                    const size_t fi = (((size_t)(MT * 10 + chunk) << 6) + lane_a) * 8 + sloti;
                    Bh8[fi] = hb;
                    Bl8[fi] = lb;
                }
            }
        }

        __syncthreads();  // all waves' stores drained (barrier implies vmcnt(0))
        if (tid == 0) {
            __threadfence();  // release: wbL2 -> data visible at MALL
            __hip_atomic_store(fpub_p, (unsigned)tt, __ATOMIC_RELAXED,
                               __HIP_MEMORY_SCOPE_AGENT);
        }
    }
}

extern "C" void kernel_launch(void* const* d_in, const int* in_sizes, int n_in,
                              void* d_out, int out_size, void* d_ws, size_t ws_size,
                              hipStream_t stream) {
    const float* h0 = (const float*)d_in[0];
    const float* c0 = (const float*)d_in[1];
    const float* start = (const float*)d_in[2];
    const float* W_ih = (const float*)d_in[3];
    const float* W_hh = (const float*)d_in[4];
    const float* b_ih = (const float*)d_in[5];
    const float* b_hh = (const float*)d_in[6];
    const float* W_out = (const float*)d_in[7];
    const float* b_out = (const float*)d_in[8];
    float* out = (float*)d_out;

    float* wsf = (float*)d_ws;
    float* W_big = wsf;               // 450000
    float* bias_big = wsf + 450000;   // 1504
    float* c_ws = wsf + 451504;       // 307200
    float* h_row = wsf + 758704;      // 307200
    short* wss = (short*)(wsf + 1065904);
    short* Wh = wss;                  // 486400
    short* Wl = wss + 486400;         // 486400
    short* H0h = wss + 972800;        // 327680
    short* H0l = wss + 1300480;       // 327680
    short* H1h = wss + 1628160;       // 327680
    short* H1l = wss + 1955840;       // 327680
    unsigned* flags = (unsigned*)(wss + 2283520);  // 152 uints used

    build_kernel<<<2816, 256, 0, stream>>>(W_out, b_out, W_big, bias_big, (unsigned int*)H0h, flags);
    fold_kernel<<<1200, 128, 0, stream>>>(W_ih, W_hh, W_out, W_big);
    bias_fold_kernel<<<1200, 64, 0, stream>>>(W_ih, b_ih, b_hh, b_out, bias_big);
    pack_w_kernel<<<950, 64, 0, stream>>>(W_big, Wh, Wl);

    // step 0 (ref iteration 0): exact fp32; h_1 -> h_row, c_1 -> c_ws
    step0_kernel<<<dim3(16, 38), 128, 0, stream>>>(start, h0, W_ih, W_hh, b_ih, b_hh,
                                                   c0, c_ws, h_row);
    convert_h_kernel<<<1280, 256, 0, stream>>>(h_row, H0h, H0l);

    // tt = 1..256 inside one barrier-free persistent kernel (152 blocks, 1/CU by LDS)
    persist_kernel<<<152, 256, 0, stream>>>(H0h, H0l, H1h, H1l, Wh, Wl,
                                            bias_big, c_ws, out, flags);
}

// Round 4
// 2610.571 us; speedup vs baseline: 2.2703x; 1.9664x over previous
//
#include <hip/hip_runtime.h>
#include <hip/hip_bf16.h>

// LSTM decoder, B=1024, H=300, 256 steps. Output fp32.
// Folded recurrence: W_fold = W_hh + W_ih@W_out (gates from h_t), y = h_t@W_out^T.
// R8: persistent kernel, NO cache-maintenance ops in the loop. R7's 16us/step of
// idle time was __threadfence (full L2 wbl2+inv per block per step). Replace with
// per-access MALL coherence: A-loads = 8B relaxed AGENT atomic loads (sc1, bypass
// stale L2, compiler-managed waits -> no R6 register hazard); h-stores = LDS
// transpose to 16B runs then 8B relaxed AGENT atomic stores (write-through MALL);
// flag = vmcnt(0) drain + relaxed AGENT store. Math identical to R5/R7.

typedef __attribute__((ext_vector_type(8))) short bf16x8;
typedef __attribute__((ext_vector_type(4))) float f32x4;
typedef __attribute__((ext_vector_type(2))) unsigned long long u64x2;
typedef unsigned long long u64;

#define MFMA16(a, b, c) __builtin_amdgcn_mfma_f32_16x16x32_bf16((a), (b), (c), 0, 0, 0)

__device__ __forceinline__ float sigf(float x) { return 1.0f / (1.0f + __expf(-x)); }
__device__ __forceinline__ float tanh_fast(float x) { return 2.0f / (1.0f + __expf(-2.0f * x)) - 1.0f; }
__device__ __forceinline__ short f2bf(float x) { __hip_bfloat16 h = __float2bfloat16(x); return *(short*)&h; }
__device__ __forceinline__ float bf2f(short s) { __hip_bfloat16 h; *(short*)&h = s; return __bfloat162float(h); }

__device__ __forceinline__ u64 lda8(const u64* p) {
    return __hip_atomic_load(p, __ATOMIC_RELAXED, __HIP_MEMORY_SCOPE_AGENT);
}
__device__ __forceinline__ void sta8(u64* p, u64 v) {
    __hip_atomic_store(p, v, __ATOMIC_RELAXED, __HIP_MEMORY_SCOPE_AGENT);
}

// ---------- precompute: zero h-frag buffers + flags, copy W_out rows + b_out ----------
__global__ void build_kernel(const float* __restrict__ W_out, const float* __restrict__ b_out,
                             float* __restrict__ W_big, float* __restrict__ bias_big,
                             unsigned int* __restrict__ hfrag_zero, unsigned int* __restrict__ flags) {
    int stride = gridDim.x * blockDim.x;
    int idx = blockIdx.x * blockDim.x + threadIdx.x;
    for (int i = idx; i < 655360; i += stride) hfrag_zero[i] = 0u;  // 4 x 327680 shorts
    for (int i = idx; i < 300 * 300; i += stride) W_big[1200 * 300 + i] = W_out[i];
    for (int i = idx; i < 300; i += stride) bias_big[1200 + i] = b_out[i];
    if (idx < 256) flags[idx] = 0u;
}

// ---------- precompute: W_big rows 0..1199 = W_hh + W_ih @ W_out ----------
__global__ __launch_bounds__(128) void fold_kernel(const float* __restrict__ W_ih,
                                                   const float* __restrict__ W_hh,
                                                   const float* __restrict__ W_out,
                                                   float* __restrict__ W_big) {
    int j = blockIdx.x;  // 0..1199
    __shared__ float row[300];
    for (int m = threadIdx.x; m < 300; m += 128) row[m] = W_ih[j * 300 + m];
    __syncthreads();
    int k0 = threadIdx.x, k1 = threadIdx.x + 128, k2 = threadIdx.x + 256;
    float a0 = 0.f, a1 = 0.f, a2 = 0.f;
    for (int m = 0; m < 300; ++m) {
        float w = row[m];
        a0 += w * W_out[m * 300 + k0];
        a1 += w * W_out[m * 300 + k1];
        if (k2 < 300) a2 += w * W_out[m * 300 + k2];
    }
    W_big[j * 300 + k0] = W_hh[j * 300 + k0] + a0;
    W_big[j * 300 + k1] = W_hh[j * 300 + k1] + a1;
    if (k2 < 300) W_big[j * 300 + k2] = W_hh[j * 300 + k2] + a2;
}

// ---------- precompute: bias_big[0..1199] = b_ih + b_hh + W_ih @ b_out ----------
__global__ __launch_bounds__(64) void bias_fold_kernel(const float* __restrict__ W_ih,
                                                       const float* __restrict__ b_ih,
                                                       const float* __restrict__ b_hh,
                                                       const float* __restrict__ b_out,
                                                       float* __restrict__ bias_big) {
    int j = blockIdx.x;  // 0..1199
    int lane = threadIdx.x;
    float s = 0.f;
    for (int m = lane; m < 300; m += 64) s += W_ih[j * 300 + m] * b_out[m];
    for (int off = 32; off > 0; off >>= 1) s += __shfl_down(s, off);
    if (lane == 0) bias_big[j] = b_ih[j] + b_hh[j] + s;
}

// ---------- precompute: pack W_big into MFMA B-fragment layout, bf16 hi/lo ----------
// tile index = (jt*5 + ch)*10 + kc ; ch 0..3 = gates (row ch*300+j), 4 = y (row 1200+j).
__global__ __launch_bounds__(64) void pack_w_kernel(const float* __restrict__ W_big,
                                                    short* __restrict__ Wh, short* __restrict__ Wl) {
    int tile = blockIdx.x;  // 0..949
    int jt = tile / 50;
    int rem = tile - jt * 50;
    int ch = rem / 10;
    int kc = rem - ch * 10;
    int lane = threadIdx.x;
    int j = jt * 16 + (lane & 15);
    int kbase = kc * 32 + (lane >> 4) * 8;
    int r = (ch < 4) ? (ch * 300 + j) : (1200 + j);
    size_t base = (size_t)tile * 512 + (size_t)lane * 8;
#pragma unroll
    for (int jj = 0; jj < 8; ++jj) {
        int k = kbase + jj;
        float v = (j < 300 && k < 300) ? W_big[(size_t)r * 300 + k] : 0.f;
        short hi = f2bf(v);
        short lo = f2bf(v - bf2f(hi));
        Wh[base + jj] = hi;
        Wl[base + jj] = lo;
    }
}

// ---------- step 0: exact fp32 VALU LSTM cell on [start | h0], K=600 ----------
__global__ __launch_bounds__(128) void step0_kernel(
    const float* __restrict__ x_in, const float* __restrict__ h_in,
    const float* __restrict__ W_ih, const float* __restrict__ W_hh,
    const float* __restrict__ b_ih, const float* __restrict__ b_hh,
    const float* __restrict__ c_in, float* __restrict__ c_out,
    float* __restrict__ h_out) {
    __shared__ float hs[16][68];
    __shared__ float wsm[16][32];
    const int t = threadIdx.x;
    const int bm0 = blockIdx.x * 64;
    const int jg0 = blockIdx.y * 8;

    const int row_idx = t & 31;
    const int wkq = (t >> 5) << 2;
    const int jl = row_idx >> 2, g = row_idx & 3;
    const int grow = jg0 + jl + 300 * g;
    const bool wvalid = (jg0 + jl) < 300;

    float acc[4][4];
#pragma unroll
    for (int i = 0; i < 4; ++i)
#pragma unroll
        for (int q = 0; q < 4; ++q) acc[i][q] = 0.f;

    for (int it = 0; it < 38; ++it) {
        const int k0 = it << 4;
#pragma unroll
        for (int q = 0; q < 2; ++q) {
            int qi = t + q * 128;
            int bl = qi >> 2;
            int kq = (qi & 3) << 2;
            int kg = k0 + kq;
            float4 hv = make_float4(0.f, 0.f, 0.f, 0.f);
            if (kg < 600) {
                const float* src = (kg < 300) ? (x_in + (size_t)(bm0 + bl) * 300 + kg)
                                              : (h_in + (size_t)(bm0 + bl) * 300 + (kg - 300));
                hv = *(const float4*)src;
            }
            hs[kq + 0][bl] = hv.x;
            hs[kq + 1][bl] = hv.y;
            hs[kq + 2][bl] = hv.z;
            hs[kq + 3][bl] = hv.w;
        }
        {
            int kg = k0 + wkq;
            float4 wv = make_float4(0.f, 0.f, 0.f, 0.f);
            if (wvalid && kg < 600) {
                const float* src = (kg < 300) ? (W_ih + (size_t)grow * 300 + kg)
                                              : (W_hh + (size_t)grow * 300 + (kg - 300));
                wv = *(const float4*)src;
            }
            wsm[wkq + 0][row_idx] = wv.x;
            wsm[wkq + 1][row_idx] = wv.y;
            wsm[wkq + 2][row_idx] = wv.z;
            wsm[wkq + 3][row_idx] = wv.w;
        }
        __syncthreads();
        const int bs4 = (t & 15) << 2;
        const int c4 = (t >> 4) << 2;
#pragma unroll
        for (int k = 0; k < 16; ++k) {
            float4 hv = *(const float4*)&hs[k][bs4];
            float4 wv = *(const float4*)&wsm[k][c4];
            float hvv[4] = {hv.x, hv.y, hv.z, hv.w};
            float wvv[4] = {wv.x, wv.y, wv.z, wv.w};
#pragma unroll
            for (int bi = 0; bi < 4; ++bi)
#pragma unroll
                for (int q = 0; q < 4; ++q) acc[bi][q] += hvv[bi] * wvv[q];
        }
        __syncthreads();
    }

    const int b0 = bm0 + ((t & 15) << 2);
    const int j = jg0 + (t >> 4);
    if (j < 300) {
        const float bi_ = b_ih[j] + b_hh[j];
        const float bf_ = b_ih[j + 300] + b_hh[j + 300];
        const float bg_ = b_ih[j + 600] + b_hh[j + 600];
        const float bo_ = b_ih[j + 900] + b_hh[j + 900];
#pragma unroll
        for (int bi = 0; bi < 4; ++bi) {
            const int b = b0 + bi;
            float ig = sigf(acc[bi][0] + bi_);
            float fg = sigf(acc[bi][1] + bf_);
            float gg = tanh_fast(acc[bi][2] + bg_);
            float og = sigf(acc[bi][3] + bo_);
            float cn = fg * c_in[(size_t)b * 300 + j] + ig * gg;
            c_out[(size_t)b * 300 + j] = cn;
            h_out[(size_t)b * 300 + j] = og * tanh_fast(cn);
        }
    }
}

// ---------- convert h fp32 -> A-fragment layout bf16 hi/lo ----------
__global__ __launch_bounds__(256) void convert_h_kernel(const float* __restrict__ h_row,
                                                        short* __restrict__ Hh, short* __restrict__ Hl) {
    int idx = blockIdx.x * 256 + threadIdx.x;  // 1024*320
    int m = idx / 320;
    int k = idx - m * 320;
    float v = (k < 300) ? h_row[(size_t)m * 300 + k] : 0.f;
    short hi = f2bf(v);
    short lo = f2bf(v - bf2f(hi));
    int chunk = k >> 5;
    int lane = (m & 15) + 16 * ((k & 31) >> 3);
    int slot = k & 7;
    size_t fi = (((size_t)(m >> 4) * 10 + chunk) * 64 + lane) * 8 + slot;
    Hh[fi] = hi;
    Hl[fi] = lo;
}

// ---------- R8 persistent kernel: 152 blocks = 8 groups x 19 jt, 256 thr (4 waves) ----------
// Wave w owns m-tiles {g*8+w, g*8+w+4}. Per-step sync: compute -> h via LDS transpose
// -> 8B AGENT atomic stores (MALL write-through) -> vmcnt(0) -> __syncthreads ->
// tid0 publishes flag (AGENT atomic). Consumers poll 19 flags (AGENT atomic loads),
// then read A-fragments with 8B AGENT atomic loads. No threadfence / L2 flush ever.
__global__ __launch_bounds__(256, 1) void persist_kernel(
    short* __restrict__ H0h, short* __restrict__ H0l,
    short* __restrict__ H1h, short* __restrict__ H1l,
    const short* __restrict__ Wph, const short* __restrict__ Wpl,
    const float* __restrict__ bias, const float* __restrict__ c_init,
    float* __restrict__ out, unsigned* __restrict__ flags) {
    __shared__ __align__(16) short w_hi[50 * 512];  // 51200 B
    __shared__ __align__(16) short w_lo[40 * 512];  // 40960 B
    __shared__ __align__(16) short hst_h[2048];     // 4096 B (h hi transpose stage)
    __shared__ __align__(16) short hst_l[2048];     // 4096 B  => 100352 B total

    const int bid = blockIdx.x;
    const int g = bid / 19;         // row group: rows g*128 .. +128
    const int jt = bid - g * 19;    // j tile: cols jt*16 .. +16
    const int tid = threadIdx.x;
    const int wave = tid >> 6;
    const int lane = tid & 63;

    // one-time: W tiles for this jt -> LDS
    {
        const int4* s1 = (const int4*)(Wph + (size_t)jt * 25600);
        int4* d1 = (int4*)w_hi;
        for (int i = tid; i < 3200; i += 256) d1[i] = s1[i];
        const int4* s2 = (const int4*)(Wpl + (size_t)jt * 25600);
        int4* d2 = (int4*)w_lo;
        for (int i = tid; i < 2560; i += 256) d2[i] = s2[i];
    }

    const int jl = lane & 15;
    const int jg = jt * 16 + jl;
    const bool jvalid = jg < 300;
    const int mr = (lane >> 4) << 2;
    const int laneo = lane << 3;

    float b_i = 0.f, b_f = 0.f, b_g = 0.f, b_o = 0.f, b_y = 0.f;
    if (jvalid) {
        b_i = bias[jg];
        b_f = bias[300 + jg];
        b_g = bias[600 + jg];
        b_o = bias[900 + jg];
        b_y = bias[1200 + jg];
    }

    const int mt0 = g * 8 + wave;   // this wave's m-tiles: mt0, mt0+4
    float c_reg[8];
#pragma unroll
    for (int mti = 0; mti < 2; ++mti)
#pragma unroll
        for (int r = 0; r < 4; ++r) {
            const int m = (mt0 + 4 * mti) * 16 + mr + r;
            c_reg[mti * 4 + r] = jvalid ? c_init[(size_t)m * 300 + jg] : 0.f;
        }

    // A addressing in u64 units: fragment (mt,kc,lane) at (mt*640 + kc*64 + lane)*2
    const int iA2 = (mt0 * 640 + lane) * 2;
    const int chunk = jt >> 1;
    unsigned* fpoll_p = flags + (g * 19 + (lane < 19 ? lane : 18));
    unsigned* fpub_p = flags + (g * 19 + jt);

    // h store-out decomposition (one 16B hi run + one 16B lo run per thread)
    const int so_mtl = tid >> 5;          // 0..7
    const int so_mrow = (tid >> 1) & 15;  // 0..15
    const int so_ha = tid & 1;            // 0..1
    const int so_off = ((so_mtl * 16 + so_mrow) * 2 + so_ha) * 8;  // shorts
    const size_t so_bi =
        ((size_t)((g * 8 + so_mtl) * 10 + chunk) * 64 + (so_mrow + ((2 * (jt & 1) + so_ha) << 4))) * 2;

    __syncthreads();  // W in LDS ready

#pragma unroll 1
    for (int tt = 1; tt <= 256; ++tt) {
        const short* Ah8 = (tt & 1) ? H0h : H1h;
        const short* Al8 = (tt & 1) ? H0l : H1l;
        short* Bh8 = (tt & 1) ? H1h : H0h;
        short* Bl8 = (tt & 1) ? H1l : H0l;
        float* yo = out + (size_t)(tt - 1) * 307200;

        // wait for the 19 producers of this group to finish step tt-1 (MALL flags)
        if (wave == 0) {
            const unsigned target = (unsigned)(tt - 1);
            while (true) {
                unsigned fv = __hip_atomic_load(fpoll_p, __ATOMIC_RELAXED,
                                                __HIP_MEMORY_SCOPE_AGENT);
                if (__all((int)((lane >= 19) | (fv >= target)))) break;
                __builtin_amdgcn_s_sleep(1);
            }
        }
        __syncthreads();

        const u64* A2h = (const u64*)Ah8 + iA2;
        const u64* A2l = (const u64*)Al8 + iA2;

        f32x4 acc[4][2];
        f32x4 accy[2];
#pragma unroll
        for (int ch = 0; ch < 4; ++ch) {
            acc[ch][0] = (f32x4){0.f, 0.f, 0.f, 0.f};
            acc[ch][1] = (f32x4){0.f, 0.f, 0.f, 0.f};
        }
        accy[0] = (f32x4){0.f, 0.f, 0.f, 0.f};
        accy[1] = (f32x4){0.f, 0.f, 0.f, 0.f};

        // 2-ahead slot rotation; all indices compile-time after full unroll.
        u64x2 p0h[3], p0l[3], p1h[3], p1l[3];
#pragma unroll
        for (int k = 0; k < 2; ++k) {
            p0h[k].x = lda8(A2h + k * 128);
            p0h[k].y = lda8(A2h + k * 128 + 1);
            p0l[k].x = lda8(A2l + k * 128);
            p0l[k].y = lda8(A2l + k * 128 + 1);
            p1h[k].x = lda8(A2h + 5120 + k * 128);
            p1h[k].y = lda8(A2h + 5120 + k * 128 + 1);
            p1l[k].x = lda8(A2l + 5120 + k * 128);
            p1l[k].y = lda8(A2l + 5120 + k * 128 + 1);
        }

#pragma unroll
        for (int kc = 0; kc < 10; ++kc) {
            const int cs = kc % 3;
            if (kc + 2 < 10) {
                const int ns = (kc + 2) % 3;
                p0h[ns].x = lda8(A2h + (kc + 2) * 128);
                p0h[ns].y = lda8(A2h + (kc + 2) * 128 + 1);
                p0l[ns].x = lda8(A2l + (kc + 2) * 128);
                p0l[ns].y = lda8(A2l + (kc + 2) * 128 + 1);
                p1h[ns].x = lda8(A2h + 5120 + (kc + 2) * 128);
                p1h[ns].y = lda8(A2h + 5120 + (kc + 2) * 128 + 1);
                p1l[ns].x = lda8(A2l + 5120 + (kc + 2) * 128);
                p1l[ns].y = lda8(A2l + 5120 + (kc + 2) * 128 + 1);
            }
            const bf16x8 a0h = (bf16x8)p0h[cs];
            const bf16x8 a0l = (bf16x8)p0l[cs];
            const bf16x8 a1h = (bf16x8)p1h[cs];
            const bf16x8 a1l = (bf16x8)p1l[cs];
#pragma unroll
            for (int ch = 0; ch < 4; ++ch) {
                const bf16x8 bh = *(const bf16x8*)(w_hi + ((ch * 10 + kc) << 9) + laneo);
                const bf16x8 bl = *(const bf16x8*)(w_lo + ((ch * 10 + kc) << 9) + laneo);
                acc[ch][0] = MFMA16(a0h, bh, acc[ch][0]);
                acc[ch][0] = MFMA16(a0l, bh, acc[ch][0]);
                acc[ch][0] = MFMA16(a0h, bl, acc[ch][0]);
                acc[ch][1] = MFMA16(a1h, bh, acc[ch][1]);
                acc[ch][1] = MFMA16(a1l, bh, acc[ch][1]);
                acc[ch][1] = MFMA16(a1h, bl, acc[ch][1]);
            }
            const bf16x8 by = *(const bf16x8*)(w_hi + ((40 + kc) << 9) + laneo);
            accy[0] = MFMA16(a0h, by, accy[0]);
            accy[0] = MFMA16(a0l, by, accy[0]);
            accy[1] = MFMA16(a1h, by, accy[1]);
            accy[1] = MFMA16(a1l, by, accy[1]);
        }

        // in-register pointwise epilogue; h -> LDS transpose stage (16B runs)
#pragma unroll
        for (int mti = 0; mti < 2; ++mti) {
            const int mt_l = wave + 4 * mti;
            const int MT = mt0 + 4 * mti;
#pragma unroll
            for (int r = 0; r < 4; ++r) {
                const float gi = acc[0][mti][r] + b_i;
                const float gf = acc[1][mti][r] + b_f;
                const float gg = acc[2][mti][r] + b_g;
                const float go_ = acc[3][mti][r] + b_o;
                const float iv = sigf(gi), fv = sigf(gf), gv = tanh_fast(gg), ov = sigf(go_);
                const float cn = fv * c_reg[mti * 4 + r] + iv * gv;
                c_reg[mti * 4 + r] = cn;
                const float hv = ov * tanh_fast(cn);
                if (jvalid) {
                    const int m = MT * 16 + mr + r;
                    __builtin_nontemporal_store(accy[mti][r] + b_y, yo + (size_t)m * 300 + jg);
                }
                const short hb = f2bf(hv);
                const short lb = f2bf(hv - bf2f(hb));
                const int si = ((mt_l * 16 + (mr + r)) * 2 + (jl >> 3)) * 8 + (jl & 7);
                hst_h[si] = hb;
                hst_l[si] = lb;
            }
        }
        __syncthreads();  // hst ready

        // store-out: one 16B hi + 16B lo run per thread via 8B AGENT atomic stores
        {
            const u64* sh = (const u64*)&hst_h[so_off];
            const u64* sl = (const u64*)&hst_l[so_off];
            sta8((u64*)Bh8 + so_bi, sh[0]);
            sta8((u64*)Bh8 + so_bi + 1, sh[1]);
            sta8((u64*)Bl8 + so_bi, sl[0]);
            sta8((u64*)Bl8 + so_bi + 1, sl[1]);
        }
        asm volatile("s_waitcnt vmcnt(0)" ::: "memory");  // stores visible at MALL
        __syncthreads();                                  // all waves drained
        if (tid == 0) {
            __hip_atomic_store(fpub_p, (unsigned)tt, __ATOMIC_RELAXED,
                               __HIP_MEMORY_SCOPE_AGENT);
        }
    }
}

extern "C" void kernel_launch(void* const* d_in, const int* in_sizes, int n_in,
                              void* d_out, int out_size, void* d_ws, size_t ws_size,
                              hipStream_t stream) {
    const float* h0 = (const float*)d_in[0];
    const float* c0 = (const float*)d_in[1];
    const float* start = (const float*)d_in[2];
    const float* W_ih = (const float*)d_in[3];
    const float* W_hh = (const float*)d_in[4];
    const float* b_ih = (const float*)d_in[5];
    const float* b_hh = (const float*)d_in[6];
    const float* W_out = (const float*)d_in[7];
    const float* b_out = (const float*)d_in[8];
    float* out = (float*)d_out;

    float* wsf = (float*)d_ws;
    float* W_big = wsf;               // 450000
    float* bias_big = wsf + 450000;   // 1504
    float* c_ws = wsf + 451504;       // 307200
    float* h_row = wsf + 758704;      // 307200
    short* wss = (short*)(wsf + 1065904);
    short* Wh = wss;                  // 486400
    short* Wl = wss + 486400;         // 486400
    short* H0h = wss + 972800;        // 327680
    short* H0l = wss + 1300480;       // 327680
    short* H1h = wss + 1628160;       // 327680
    short* H1l = wss + 1955840;       // 327680
    unsigned* flags = (unsigned*)(wss + 2283520);  // 152 uints used

    build_kernel<<<2816, 256, 0, stream>>>(W_out, b_out, W_big, bias_big, (unsigned int*)H0h, flags);
    fold_kernel<<<1200, 128, 0, stream>>>(W_ih, W_hh, W_out, W_big);
    bias_fold_kernel<<<1200, 64, 0, stream>>>(W_ih, b_ih, b_hh, b_out, bias_big);
    pack_w_kernel<<<950, 64, 0, stream>>>(W_big, Wh, Wl);

    // step 0 (ref iteration 0): exact fp32; h_1 -> h_row, c_1 -> c_ws
    step0_kernel<<<dim3(16, 38), 128, 0, stream>>>(start, h0, W_ih, W_hh, b_ih, b_hh,
                                                   c0, c_ws, h_row);
    convert_h_kernel<<<1280, 256, 0, stream>>>(h_row, H0h, H0l);

    // tt = 1..256 inside one fence-free persistent kernel (152 blocks, 1/CU by LDS)
    persist_kernel<<<152, 256, 0, stream>>>(H0h, H0l, H1h, H1l, Wh, Wl,
                                            bias_big, c_ws, out, flags);
}